// Round 1
// baseline (633.663 us; speedup 1.0000x reference)
//
#include <hip/hip_runtime.h>
#include <math.h>

#define HEADS 4
#define BATCH 8
#define SEQ   1024
#define CH    256
#define DH    64      // head dim
#define RROWS 8       // q rows per block
#define MCH   64      // key/value chunk
#define NTHR  256

// Detect whether the mask buffer is int32 (harness converted bool->int32) or
// raw 1-byte bool. int32 0/1 values => every non-4-aligned byte is 0.
// Raw bool with random 0/1 => nonzero bytes at misaligned offsets, certainly
// within the first 4096 bytes. Probing 4096 bytes is safe for both layouts
// (buffer is at least 8M bytes either way). flag=1 => byte mask, 0 => int32.
__global__ void detect_mask_kernel(const unsigned char* __restrict__ mb,
                                   int* __restrict__ flag) {
    int t = threadIdx.x;
    int found = 0;
    for (int o = t * 64; o < t * 64 + 64; ++o) {
        if ((o & 3) != 0 && mb[o] != 0) found = 1;
    }
    unsigned long long ball = __ballot(found != 0);
    if (t == 0) flag[0] = (ball != 0ULL) ? 1 : 0;
}

__global__ __launch_bounds__(NTHR)
void attn_kernel(const float* __restrict__ q, const float* __restrict__ k,
                 const float* __restrict__ v, const void* __restrict__ maskp,
                 const float* __restrict__ dis, float* __restrict__ out,
                 float* __restrict__ pout, const int* __restrict__ flag)
{
    __shared__ float Qs[RROWS][DH];       // 2 KB
    __shared__ float Ks[MCH][DH + 1];     // 16.6 KB, +1 pad: (tm+kk)%32 banks
    __shared__ float S[RROWS][SEQ];       // 32 KB score slab
    __shared__ float red[RROWS];          // 1/rowsum

    const int t   = threadIdx.x;
    const int bid = blockIdx.x;
    const int nb  = bid & (SEQ / RROWS - 1);   // 128 slabs per (h,b)
    const int hb  = bid >> 7;
    const int b   = hb & (BATCH - 1);
    const int h   = hb >> 3;
    const int n0  = nb * RROWS;
    const int fl  = flag[0];
    const unsigned char* mask8  = (const unsigned char*)maskp;
    const int*           mask32 = (const int*)maskp;

    // ---- load Q slab (coalesced rows of 64 floats) ----
    {
        int e = t;
        #pragma unroll
        for (int i = 0; i < RROWS * DH / NTHR; ++i) {
            int r = e >> 6, j = e & 63;
            Qs[r][j] = q[((size_t)(b * SEQ + n0 + r)) * CH + h * DH + j];
            e += NTHR;
        }
    }

    const int tm = t & 63;     // m-lane within chunk / output column
    const int rg = t >> 6;     // wave id -> wave-uniform row pair
    const int r0 = rg * 2, r1 = r0 + 1;
    const float* kbase = k + ((size_t)(b * SEQ)) * CH + h * DH;

    // ---- QK^T phase: S[r][m] = mask ? -inf : (q.k + dis)/8 ----
    for (int mc = 0; mc < SEQ; mc += MCH) {
        __syncthreads();   // previous chunk's readers done before overwrite
        #pragma unroll
        for (int i = 0; i < 4; ++i) {
            int s  = t + NTHR * i;          // 1024 float4 slots
            int m  = s >> 4;
            int j4 = (s & 15) * 4;
            const float4 kv4 = *(const float4*)(kbase + (size_t)(mc + m) * CH + j4);
            Ks[m][j4 + 0] = kv4.x; Ks[m][j4 + 1] = kv4.y;
            Ks[m][j4 + 2] = kv4.z; Ks[m][j4 + 3] = kv4.w;
        }
        __syncthreads();
        float a0 = 0.f, a1 = 0.f;
        #pragma unroll 16
        for (int kk = 0; kk < DH; ++kk) {
            float kv = Ks[tm][kk];              // conflict-free (pad 65)
            a0 = fmaf(Qs[r0][kk], kv, a0);      // wave-uniform broadcast
            a1 = fmaf(Qs[r1][kk], kv, a1);
        }
        const int mg = mc + tm;
        const size_t di0 = ((size_t)(b * SEQ + n0 + r0)) * SEQ + mg;
        const size_t di1 = ((size_t)(b * SEQ + n0 + r1)) * SEQ + mg;
        const bool mk0 = fl ? (mask8[di0] != 0) : (mask32[di0] != 0);
        const bool mk1 = fl ? (mask8[di1] != 0) : (mask32[di1] != 0);
        S[r0][mg] = mk0 ? -INFINITY : (a0 + dis[di0]) * 0.125f;
        S[r1][mg] = mk1 ? -INFINITY : (a1 + dis[di1]) * 0.125f;
    }
    __syncthreads();

    // ---- softmax per row: 32 lanes per row ----
    {
        const int r = t >> 5, l = t & 31;
        float mx = -INFINITY;
        #pragma unroll
        for (int j = 0; j < SEQ / 32; ++j) mx = fmaxf(mx, S[r][l + 32 * j]);
        #pragma unroll
        for (int off = 16; off > 0; off >>= 1) mx = fmaxf(mx, __shfl_down(mx, off, 32));
        mx = __shfl(mx, 0, 32);
        float sm = 0.f;
        #pragma unroll
        for (int j = 0; j < SEQ / 32; ++j) {
            int m = l + 32 * j;
            float e = __expf(S[r][m] - mx);   // exp(-inf)=0 handles mask
            S[r][m] = e;
            sm += e;
        }
        #pragma unroll
        for (int off = 16; off > 0; off >>= 1) sm += __shfl_down(sm, off, 32);
        if (l == 0) red[r] = 1.0f / sm;
    }
    __syncthreads();

    // ---- write normalized p_attn (coalesced float4) ----
    {
        float* prow = pout + ((size_t)((h * BATCH + b) * SEQ + n0)) * SEQ;
        #pragma unroll
        for (int j = 0; j < RROWS; ++j) {
            const float inv = red[j];
            float4 p4 = *(const float4*)&S[j][t * 4];
            p4.x *= inv; p4.y *= inv; p4.z *= inv; p4.w *= inv;
            *(float4*)(prow + (size_t)j * SEQ + t * 4) = p4;
        }
    }

    // ---- PV phase: out[r][j] = inv[r] * sum_m e[r][m] * V[m][j] ----
    const float* vbase = v + ((size_t)(b * SEQ)) * CH + h * DH;
    float o0 = 0.f, o1 = 0.f;
    for (int mc = 0; mc < SEQ; mc += MCH) {
        __syncthreads();
        #pragma unroll
        for (int i = 0; i < 4; ++i) {
            int s  = t + NTHR * i;
            int m  = s >> 4;
            int j4 = (s & 15) * 4;
            const float4 vv4 = *(const float4*)(vbase + (size_t)(mc + m) * CH + j4);
            Ks[m][j4 + 0] = vv4.x; Ks[m][j4 + 1] = vv4.y;
            Ks[m][j4 + 2] = vv4.z; Ks[m][j4 + 3] = vv4.w;
        }
        __syncthreads();
        #pragma unroll 16
        for (int mm = 0; mm < MCH; ++mm) {
            float vv = Ks[mm][tm];              // conflict-free (pad 65)
            o0 = fmaf(S[r0][mc + mm], vv, o0);  // broadcast
            o1 = fmaf(S[r1][mc + mm], vv, o1);
        }
    }
    const float i0 = red[r0], i1 = red[r1];
    out[((size_t)(b * SEQ + n0 + r0)) * CH + h * DH + tm] = o0 * i0;
    out[((size_t)(b * SEQ + n0 + r1)) * CH + h * DH + tm] = o1 * i1;
}

extern "C" void kernel_launch(void* const* d_in, const int* in_sizes, int n_in,
                              void* d_out, int out_size, void* d_ws, size_t ws_size,
                              hipStream_t stream) {
    const float* q    = (const float*)d_in[0];
    const float* k    = (const float*)d_in[1];
    const float* v    = (const float*)d_in[2];
    const void*  mask = d_in[3];
    const float* dis  = (const float*)d_in[4];
    float* out  = (float*)d_out;
    float* pout = out + (size_t)BATCH * SEQ * CH;   // p_attn after out
    int*   flag = (int*)d_ws;

    detect_mask_kernel<<<1, 64, 0, stream>>>((const unsigned char*)mask, flag);
    attn_kernel<<<HEADS * BATCH * (SEQ / RROWS), NTHR, 0, stream>>>(
        q, k, v, mask, dis, out, pout, flag);
}

// Round 2
// 432.457 us; speedup vs baseline: 1.4653x; 1.4653x over previous
//
#include <hip/hip_runtime.h>
#include <math.h>

#define HEADS 4
#define BATCH 8
#define SEQ   1024
#define CH    256
#define DH    64
#define RB    16          // q rows per block
#define MC    64          // k/v rows per staged chunk
#define NTHR  256
#define KSTR  72          // Qs/KVs row stride in bf16 elems (144 B, 16B-mult)
#define SSTR  (SEQ + 8)   // Sraw row stride in bf16 elems (2064 B, 16B-mult)

typedef float  floatx4  __attribute__((ext_vector_type(4)));
typedef short  shortx8  __attribute__((ext_vector_type(8)));
typedef unsigned short ushortx4 __attribute__((ext_vector_type(4)));

__device__ __forceinline__ unsigned short f2bf(float f) {
    unsigned u = __float_as_uint(f);
    unsigned r = u + 0x7FFFu + ((u >> 16) & 1u);   // RNE; -inf stays -inf
    return (unsigned short)(r >> 16);
}
__device__ __forceinline__ float bf2f(unsigned short h) {
    return __uint_as_float(((unsigned)h) << 16);
}

// mask dtype detector: int32-encoded bool has all non-word-aligned bytes zero.
__global__ void detect_mask_kernel(const unsigned char* __restrict__ mb,
                                   int* __restrict__ flag) {
    int t = threadIdx.x;
    int found = 0;
    for (int o = t * 64; o < t * 64 + 64; ++o)
        if ((o & 3) != 0 && mb[o] != 0) found = 1;
    unsigned long long ball = __ballot(found != 0);
    if (t == 0) flag[0] = (ball != 0ULL) ? 1 : 0;   // 1 => byte mask
}

__global__ __launch_bounds__(NTHR, 3)
void attn_mfma(const float* __restrict__ q, const float* __restrict__ k,
               const float* __restrict__ v, const void* __restrict__ maskp,
               const float* __restrict__ dis, float* __restrict__ out,
               float* __restrict__ pout, const int* __restrict__ flag)
{
    __shared__ unsigned short Qs[RB][KSTR];      // 2304 B
    __shared__ unsigned short KVs[MC][KSTR];     // 9216 B (K then V chunks)
    __shared__ unsigned short Sraw[RB][SSTR];    // 33024 B raw scores -> exp
    __shared__ float invs[RB];

    const int t   = threadIdx.x;
    const int bid = blockIdx.x;
    const int nb  = bid & 63;          // 64 row-tiles per (h,b)
    const int hb  = bid >> 6;
    const int b   = hb & (BATCH - 1);
    const int h   = hb >> 3;
    const int n0  = nb * RB;
    const int fl  = flag[0];
    const unsigned char* mask8  = (const unsigned char*)maskp;
    const int*           mask32 = (const int*)maskp;

    const int lane = t & 63;
    const int w    = t >> 6;       // wave id 0..3 -> 16-col slice
    const int ln   = lane & 15;    // fragment m / n index
    const int qd   = lane >> 4;    // quad -> k-group / D row group

    // ---- stage Q tile (16 x 64) as bf16 ----
    {
        int r = t >> 4, c0 = (t & 15) * 4;
        float4 qv = *(const float4*)(q + ((size_t)(b * SEQ + n0 + r)) * CH + h * DH + c0);
        ushortx4 p = { f2bf(qv.x), f2bf(qv.y), f2bf(qv.z), f2bf(qv.w) };
        *(ushortx4*)&Qs[r][c0] = p;
    }
    __syncthreads();

    // persistent A-frags for QK^T: A[m=ln][k=qd*8+j], k-steps 0 and 32
    shortx8 aq0 = *(const shortx8*)&Qs[ln][qd * 8];
    shortx8 aq1 = *(const shortx8*)&Qs[ln][32 + qd * 8];

    const float* kbase = k + ((size_t)(b * SEQ)) * CH + h * DH;
    const float* vbase = v + ((size_t)(b * SEQ)) * CH + h * DH;

    // ---- Pass 1: S = mask ? -inf : (Q K^T + dis)/8, stored bf16 in LDS ----
    for (int mc = 0; mc < SEQ / MC; ++mc) {
        __syncthreads();                       // prev chunk frag reads done
        #pragma unroll
        for (int i = 0; i < 4; ++i) {          // stage 64 K rows, bf16
            int s = t + NTHR * i;
            int r = s >> 4, c0 = (s & 15) * 4;
            float4 kv = *(const float4*)(kbase + ((size_t)(mc * MC + r)) * CH + c0);
            ushortx4 p = { f2bf(kv.x), f2bf(kv.y), f2bf(kv.z), f2bf(kv.w) };
            *(ushortx4*)&KVs[r][c0] = p;
        }
        __syncthreads();
        // B[k=qd*8+j][n=ln] = K[cw+n][k]
        shortx8 b0 = *(const shortx8*)&KVs[w * 16 + ln][qd * 8];
        shortx8 b1 = *(const shortx8*)&KVs[w * 16 + ln][32 + qd * 8];
        floatx4 acc = {0.f, 0.f, 0.f, 0.f};
        acc = __builtin_amdgcn_mfma_f32_16x16x32_bf16(aq0, b0, acc, 0, 0, 0);
        acc = __builtin_amdgcn_mfma_f32_16x16x32_bf16(aq1, b1, acc, 0, 0, 0);
        const int mg = mc * MC + w * 16 + ln;  // global score col
        #pragma unroll
        for (int r = 0; r < 4; ++r) {          // D: col=ln, row=qd*4+r
            int row = qd * 4 + r;
            size_t di = ((size_t)(b * SEQ + n0 + row)) * SEQ + mg;
            bool mk = fl ? (mask8[di] != 0) : (mask32[di] != 0);
            float sc = mk ? -INFINITY : (acc[r] + dis[di]) * 0.125f;
            Sraw[row][mg] = f2bf(sc);
        }
    }
    __syncthreads();

    // ---- Pass 2: softmax per row (16 threads / row), exp stored in-place ----
    {
        const int r = t >> 4, l = t & 15;
        float mx = -INFINITY;
        #pragma unroll
        for (int j = 0; j < 8; ++j) {
            shortx8 sv = *(const shortx8*)&Sraw[r][j * 128 + l * 8];
            #pragma unroll
            for (int e = 0; e < 8; ++e) mx = fmaxf(mx, bf2f((unsigned short)sv[e]));
        }
        #pragma unroll
        for (int off = 8; off; off >>= 1) mx = fmaxf(mx, __shfl_xor(mx, off, 16));
        float sum = 0.f;
        #pragma unroll
        for (int j = 0; j < 8; ++j) {
            shortx8 sv = *(const shortx8*)&Sraw[r][j * 128 + l * 8];
            shortx8 ev;
            #pragma unroll
            for (int e = 0; e < 8; ++e) {
                float x = __expf(bf2f((unsigned short)sv[e]) - mx);  // exp(-inf)=0
                sum += x;
                ev[e] = (short)f2bf(x);
            }
            *(shortx8*)&Sraw[r][j * 128 + l * 8] = ev;
        }
        #pragma unroll
        for (int off = 8; off; off >>= 1) sum += __shfl_xor(sum, off, 16);
        if (l == 0) invs[r] = 1.0f / sum;
    }
    __syncthreads();

    // ---- Pass 2b: write normalized p_attn (float4 coalesced) ----
    {
        float* prow = pout + ((size_t)((h * BATCH + b) * SEQ + n0)) * SEQ;
        #pragma unroll
        for (int i = 0; i < RB; ++i) {
            const float inv = invs[i];
            const unsigned short* sp = &Sraw[i][t * 4];
            float4 pv = { bf2f(sp[0]) * inv, bf2f(sp[1]) * inv,
                          bf2f(sp[2]) * inv, bf2f(sp[3]) * inv };
            *(float4*)(prow + (size_t)i * SEQ + t * 4) = pv;
        }
    }

    // ---- Pass 3: O = (E V) * inv ----
    floatx4 acco = {0.f, 0.f, 0.f, 0.f};
    for (int mc = 0; mc < SEQ / MC; ++mc) {
        __syncthreads();
        #pragma unroll
        for (int i = 0; i < 4; ++i) {          // stage 64 V rows, bf16 row-major
            int s = t + NTHR * i;
            int r = s >> 4, c0 = (s & 15) * 4;
            float4 vv = *(const float4*)(vbase + ((size_t)(mc * MC + r)) * CH + c0);
            ushortx4 p = { f2bf(vv.x), f2bf(vv.y), f2bf(vv.z), f2bf(vv.w) };
            *(ushortx4*)&KVs[r][c0] = p;
        }
        __syncthreads();
        #pragma unroll
        for (int s = 0; s < 2; ++s) {
            // A[m=ln][k] = E from LDS (C->A layout round-trip)
            shortx8 af = *(const shortx8*)&Sraw[ln][mc * MC + s * 32 + qd * 8];
            shortx8 bfv;
            #pragma unroll
            for (int j = 0; j < 8; ++j)        // B[k][n=ln] = V[k][w*16+ln]
                bfv[j] = (short)KVs[s * 32 + qd * 8 + j][w * 16 + ln];
            acco = __builtin_amdgcn_mfma_f32_16x16x32_bf16(af, bfv, acco, 0, 0, 0);
        }
    }
    #pragma unroll
    for (int r = 0; r < 4; ++r) {
        int row = qd * 4 + r;
        out[((size_t)(b * SEQ + n0 + row)) * CH + h * DH + w * 16 + ln]
            = acco[r] * invs[row];
    }
}

extern "C" void kernel_launch(void* const* d_in, const int* in_sizes, int n_in,
                              void* d_out, int out_size, void* d_ws, size_t ws_size,
                              hipStream_t stream) {
    const float* q    = (const float*)d_in[0];
    const float* k    = (const float*)d_in[1];
    const float* v    = (const float*)d_in[2];
    const void*  mask = d_in[3];
    const float* dis  = (const float*)d_in[4];
    float* out  = (float*)d_out;
    float* pout = out + (size_t)BATCH * SEQ * CH;   // p_attn after out
    int*   flag = (int*)d_ws;

    detect_mask_kernel<<<1, 64, 0, stream>>>((const unsigned char*)mask, flag);
    attn_mfma<<<HEADS * BATCH * (SEQ / RB), NTHR, 0, stream>>>(
        q, k, v, mask, dis, out, pout, flag);
}

// Round 3
// 315.139 us; speedup vs baseline: 2.0107x; 1.3723x over previous
//
#include <hip/hip_runtime.h>
#include <math.h>

#define HEADS 4
#define BATCH 8
#define SEQ   1024
#define CH    256
#define DH    64
#define RB    16          // q rows per block
#define MC    64          // score cols per chunk iter (16 per wave)
#define NTHR  256
#define SSTR  1032        // Sraw row stride in u16 (2064 B, 16B-mult)

typedef float  floatx4  __attribute__((ext_vector_type(4)));
typedef short  shortx8  __attribute__((ext_vector_type(8)));
typedef unsigned short ushortx4 __attribute__((ext_vector_type(4)));

__device__ __forceinline__ unsigned short f2bf(float f) {
    unsigned u = __float_as_uint(f);
    unsigned r = u + 0x7FFFu + ((u >> 16) & 1u);   // RNE; -inf stays -inf
    return (unsigned short)(r >> 16);
}
__device__ __forceinline__ float bf2f(unsigned short h) {
    return __uint_as_float(((unsigned)h) << 16);
}
__device__ __forceinline__ shortx8 pack8(float4 a, float4 b) {
    shortx8 r;
    r[0] = (short)f2bf(a.x); r[1] = (short)f2bf(a.y);
    r[2] = (short)f2bf(a.z); r[3] = (short)f2bf(a.w);
    r[4] = (short)f2bf(b.x); r[5] = (short)f2bf(b.y);
    r[6] = (short)f2bf(b.z); r[7] = (short)f2bf(b.w);
    return r;
}

// mask dtype detector: int32-encoded bool has all non-word-aligned bytes zero.
__global__ void detect_mask_kernel(const unsigned char* __restrict__ mb,
                                   int* __restrict__ flag) {
    int t = threadIdx.x;
    int found = 0;
    for (int o = t * 64; o < t * 64 + 64; ++o)
        if ((o & 3) != 0 && mb[o] != 0) found = 1;
    unsigned long long ball = __ballot(found != 0);
    if (t == 0) flag[0] = (ball != 0ULL) ? 1 : 0;   // 1 => byte mask
}

__global__ __launch_bounds__(NTHR, 4)
void attn_mfma(const float* __restrict__ q, const float* __restrict__ k,
               const float* __restrict__ v, const void* __restrict__ maskp,
               const float* __restrict__ dis, float* __restrict__ out,
               float* __restrict__ pout, const int* __restrict__ flag)
{
    __shared__ unsigned short Sraw[RB][SSTR];    // 33 KB: raw scores -> exp
    __shared__ float invs[RB];

    const int t   = threadIdx.x;
    const int bid = blockIdx.x;
    const int nb  = bid & 63;          // 64 row-tiles per (h,b)
    const int hb  = bid >> 6;
    const int b   = hb & (BATCH - 1);
    const int h   = hb >> 3;
    const int n0  = nb * RB;
    const int fl  = flag[0];
    const unsigned char* mask8  = (const unsigned char*)maskp;
    const int*           mask32 = (const int*)maskp;

    const int lane = t & 63;
    const int w    = t >> 6;       // wave id -> 16-col slice of each chunk
    const int ln   = lane & 15;    // fragment m / n index
    const int qd   = lane >> 4;    // quad -> k-group / D row group

    // ---- Q A-frags straight from global (L2/L3; no LDS, no barrier) ----
    // A[m=ln][k=qd*8+j], k-halves 0 and 32
    const float* qrow = q + ((size_t)(b * SEQ + n0 + ln)) * CH + h * DH;
    shortx8 aq0, aq1;
    {
        float4 a0 = *(const float4*)(qrow + qd * 8);
        float4 a1 = *(const float4*)(qrow + qd * 8 + 4);
        float4 a2 = *(const float4*)(qrow + 32 + qd * 8);
        float4 a3 = *(const float4*)(qrow + 32 + qd * 8 + 4);
        aq0 = pack8(a0, a1);
        aq1 = pack8(a2, a3);
    }

    const float* kbase = k + ((size_t)(b * SEQ)) * CH + h * DH;
    const float* vbase = v + ((size_t)(b * SEQ)) * CH + h * DH;

    // ---- Pass 1: S = mask ? -inf : (Q K^T + dis)/8 -> bf16 LDS. NO barriers.
    for (int mc = 0; mc < SEQ / MC; ++mc) {
        const int mg = mc * MC + w * 16 + ln;         // score col == K row
        const float* krow = kbase + (size_t)mg * CH;
        // issue all global loads up front (K row slice + dis + mask)
        float4 k0 = *(const float4*)(krow + qd * 8);
        float4 k1 = *(const float4*)(krow + qd * 8 + 4);
        float4 k2 = *(const float4*)(krow + 32 + qd * 8);
        float4 k3 = *(const float4*)(krow + 32 + qd * 8 + 4);
        const size_t dibase = ((size_t)(b * SEQ + n0 + qd * 4)) * SEQ + mg;
        float dv[4]; int mk[4];
        if (fl) {
            #pragma unroll
            for (int r = 0; r < 4; ++r) mk[r] = mask8[dibase + (size_t)r * SEQ];
        } else {
            #pragma unroll
            for (int r = 0; r < 4; ++r) mk[r] = mask32[dibase + (size_t)r * SEQ];
        }
        #pragma unroll
        for (int r = 0; r < 4; ++r) dv[r] = dis[dibase + (size_t)r * SEQ];

        shortx8 b0 = pack8(k0, k1), b1 = pack8(k2, k3);
        floatx4 acc = {0.f, 0.f, 0.f, 0.f};
        acc = __builtin_amdgcn_mfma_f32_16x16x32_bf16(aq0, b0, acc, 0, 0, 0);
        acc = __builtin_amdgcn_mfma_f32_16x16x32_bf16(aq1, b1, acc, 0, 0, 0);
        #pragma unroll
        for (int r = 0; r < 4; ++r) {                 // D: col=ln, row=qd*4+r
            float sc = mk[r] ? -INFINITY : (acc[r] + dv[r]) * 0.125f;
            Sraw[qd * 4 + r][mg] = f2bf(sc);
        }
    }
    __syncthreads();

    // ---- Pass 2: softmax per row (16 threads/row), exp stored in-place ----
    {
        const int r = t >> 4, l = t & 15;
        float mx = -INFINITY;
        #pragma unroll
        for (int j = 0; j < 8; ++j) {
            shortx8 sv = *(const shortx8*)&Sraw[r][j * 128 + l * 8];
            #pragma unroll
            for (int e = 0; e < 8; ++e) mx = fmaxf(mx, bf2f((unsigned short)sv[e]));
        }
        #pragma unroll
        for (int off = 8; off; off >>= 1) mx = fmaxf(mx, __shfl_xor(mx, off, 16));
        float sum = 0.f;
        #pragma unroll
        for (int j = 0; j < 8; ++j) {
            shortx8 sv = *(const shortx8*)&Sraw[r][j * 128 + l * 8];
            shortx8 ev;
            #pragma unroll
            for (int e = 0; e < 8; ++e) {
                float x = __expf(bf2f((unsigned short)sv[e]) - mx);  // exp(-inf)=0
                sum += x;
                ev[e] = (short)f2bf(x);
            }
            *(shortx8*)&Sraw[r][j * 128 + l * 8] = ev;
        }
        #pragma unroll
        for (int off = 8; off; off >>= 1) sum += __shfl_xor(sum, off, 16);
        if (l == 0) invs[r] = 1.0f / sum;
    }
    __syncthreads();

    // ---- Pass 2b: write normalized p_attn (float4 coalesced) ----
    {
        float* prow = pout + ((size_t)((h * BATCH + b) * SEQ + n0)) * SEQ;
        #pragma unroll
        for (int i = 0; i < RB; ++i) {
            const float inv = invs[i];
            ushortx4 sp = *(const ushortx4*)&Sraw[i][t * 4];
            float4 pv = { bf2f(sp[0]) * inv, bf2f(sp[1]) * inv,
                          bf2f(sp[2]) * inv, bf2f(sp[3]) * inv };
            *(float4*)(prow + (size_t)i * SEQ + t * 4) = pv;
        }
    }

    // ---- Pass 3: O = (E V) * inv. A from LDS, B gathered from global (L2).
    floatx4 acco = {0.f, 0.f, 0.f, 0.f};
    for (int mc = 0; mc < SEQ / MC; ++mc) {
        #pragma unroll
        for (int s = 0; s < 2; ++s) {
            const int kb = mc * MC + s * 32 + qd * 8;  // global k-row base
            // B[k=qd*8+j][n=ln] = V[kb+j][w*16+ln] — 8 strided dwords (L2)
            float vv[8];
            #pragma unroll
            for (int j = 0; j < 8; ++j)
                vv[j] = vbase[(size_t)(kb + j) * CH + w * 16 + ln];
            shortx8 af = *(const shortx8*)&Sraw[ln][mc * MC + s * 32 + qd * 8];
            shortx8 bfv;
            #pragma unroll
            for (int j = 0; j < 8; ++j) bfv[j] = (short)f2bf(vv[j]);
            acco = __builtin_amdgcn_mfma_f32_16x16x32_bf16(af, bfv, acco, 0, 0, 0);
        }
    }
    #pragma unroll
    for (int r = 0; r < 4; ++r) {
        int row = qd * 4 + r;
        out[((size_t)(b * SEQ + n0 + row)) * CH + h * DH + w * 16 + ln]
            = acco[r] * invs[row];
    }
}

extern "C" void kernel_launch(void* const* d_in, const int* in_sizes, int n_in,
                              void* d_out, int out_size, void* d_ws, size_t ws_size,
                              hipStream_t stream) {
    const float* q    = (const float*)d_in[0];
    const float* k    = (const float*)d_in[1];
    const float* v    = (const float*)d_in[2];
    const void*  mask = d_in[3];
    const float* dis  = (const float*)d_in[4];
    float* out  = (float*)d_out;
    float* pout = out + (size_t)BATCH * SEQ * CH;   // p_attn after out
    int*   flag = (int*)d_ws;

    detect_mask_kernel<<<1, 64, 0, stream>>>((const unsigned char*)mask, flag);
    attn_mfma<<<HEADS * BATCH * (SEQ / RB), NTHR, 0, stream>>>(
        q, k, v, mask, dis, out, pout, flag);
}

// Round 4
// 310.661 us; speedup vs baseline: 2.0397x; 1.0144x over previous
//
#include <hip/hip_runtime.h>
#include <math.h>

#define HEADS 4
#define BATCH 8
#define SEQ   1024
#define CH    256
#define DH    64
#define RB    16          // q rows per block
#define NTHR  512         // 8 waves
#define SSTR  1032        // Sraw row stride in u16 (2064 B, 16B-mult)

typedef float  floatx4  __attribute__((ext_vector_type(4)));
typedef short  shortx8  __attribute__((ext_vector_type(8)));

__device__ __forceinline__ unsigned short f2bf(float f) {
    unsigned u = __float_as_uint(f);
    unsigned r = u + 0x7FFFu + ((u >> 16) & 1u);   // RNE; -inf stays -inf
    return (unsigned short)(r >> 16);
}
__device__ __forceinline__ float bf2f(unsigned short h) {
    return __uint_as_float(((unsigned)h) << 16);
}
__device__ __forceinline__ shortx8 pack8(float4 a, float4 b) {
    shortx8 r;
    r[0] = (short)f2bf(a.x); r[1] = (short)f2bf(a.y);
    r[2] = (short)f2bf(a.z); r[3] = (short)f2bf(a.w);
    r[4] = (short)f2bf(b.x); r[5] = (short)f2bf(b.y);
    r[6] = (short)f2bf(b.z); r[7] = (short)f2bf(b.w);
    return r;
}

__global__ __launch_bounds__(NTHR, 8)
void attn_mfma(const float* __restrict__ q, const float* __restrict__ k,
               const float* __restrict__ v, const void* __restrict__ maskp,
               const float* __restrict__ dis, float* __restrict__ out,
               float* __restrict__ pout)
{
    __shared__ unsigned short Sraw[RB][SSTR];    // 33 KB: raw scores -> exp
    __shared__ float Opart[RB][65];              // 4.2 KB partial O (pad 65)
    __shared__ float invs[RB];

    const int t   = threadIdx.x;
    const int bid = blockIdx.x;
    const int nb  = bid & 63;          // 64 row-tiles per (h,b)
    const int hb  = bid >> 6;
    const int b   = hb & (BATCH - 1);
    const int h   = hb >> 3;
    const int n0  = nb * RB;

    const int lane = t & 63;
    const int w    = t >> 6;       // wave 0..7
    const int ln   = lane & 15;    // fragment m / n index
    const int qd   = lane >> 4;    // quad -> k-group / D row group

    // ---- inline mask-dtype detect: int32 bool => misaligned bytes all 0.
    // Each wave probes the same leading 4 KB (L2 broadcast), ballot -> uniform.
    int fl;
    {
        const unsigned* mw = (const unsigned*)maskp;
        int found = 0;
        #pragma unroll
        for (int j = 0; j < 16; ++j)
            if (mw[lane * 16 + j] & 0xFFFFFF00u) found = 1;
        fl = (__ballot(found != 0) != 0ULL) ? 1 : 0;   // 1 => byte mask
    }
    const unsigned char* mask8  = (const unsigned char*)maskp;
    const int*           mask32 = (const int*)maskp;

    // ---- Q A-frags straight from global (L2; no LDS, no barrier) ----
    const float* qrow = q + ((size_t)(b * SEQ + n0 + ln)) * CH + h * DH;
    shortx8 aq0, aq1;
    {
        float4 a0 = *(const float4*)(qrow + qd * 8);
        float4 a1 = *(const float4*)(qrow + qd * 8 + 4);
        float4 a2 = *(const float4*)(qrow + 32 + qd * 8);
        float4 a3 = *(const float4*)(qrow + 32 + qd * 8 + 4);
        aq0 = pack8(a0, a1);
        aq1 = pack8(a2, a3);
    }

    const float* kbase = k + ((size_t)(b * SEQ)) * CH + h * DH;
    const float* vbase = v + ((size_t)(b * SEQ)) * CH + h * DH;

    // ---- Pass 1: S = mask ? -inf : (Q K^T + dis)/8 -> bf16 LDS. No barriers.
    // 8 waves x 16 cols = 128 cols per iter, 8 iters.
    #pragma unroll 2
    for (int mc = 0; mc < 8; ++mc) {
        const int mg = mc * 128 + w * 16 + ln;        // score col == K row
        // issue cold (HBM) dis/mask loads first
        const size_t dibase = ((size_t)(b * SEQ + n0 + qd * 4)) * SEQ + mg;
        float dv[4]; int mk[4];
        #pragma unroll
        for (int r = 0; r < 4; ++r) dv[r] = dis[dibase + (size_t)r * SEQ];
        if (fl) {
            #pragma unroll
            for (int r = 0; r < 4; ++r) mk[r] = mask8[dibase + (size_t)r * SEQ];
        } else {
            #pragma unroll
            for (int r = 0; r < 4; ++r) mk[r] = mask32[dibase + (size_t)r * SEQ];
        }
        const float* krow = kbase + (size_t)mg * CH;  // L2-resident
        float4 k0 = *(const float4*)(krow + qd * 8);
        float4 k1 = *(const float4*)(krow + qd * 8 + 4);
        float4 k2 = *(const float4*)(krow + 32 + qd * 8);
        float4 k3 = *(const float4*)(krow + 32 + qd * 8 + 4);

        shortx8 b0 = pack8(k0, k1), b1 = pack8(k2, k3);
        floatx4 acc = {0.f, 0.f, 0.f, 0.f};
        acc = __builtin_amdgcn_mfma_f32_16x16x32_bf16(aq0, b0, acc, 0, 0, 0);
        acc = __builtin_amdgcn_mfma_f32_16x16x32_bf16(aq1, b1, acc, 0, 0, 0);
        #pragma unroll
        for (int r = 0; r < 4; ++r) {                 // D: col=ln, row=qd*4+r
            float sc = mk[r] ? -INFINITY : (acc[r] + dv[r]) * 0.125f;
            Sraw[qd * 4 + r][mg] = f2bf(sc);
        }
    }
    __syncthreads();

    // ---- Pass 2: softmax per row (32 threads/row), exp stored in-place ----
    {
        const int r = t >> 5, l = t & 31;
        float mx = -INFINITY;
        #pragma unroll
        for (int j = 0; j < 4; ++j) {
            shortx8 sv = *(const shortx8*)&Sraw[r][j * 256 + l * 8];
            #pragma unroll
            for (int e = 0; e < 8; ++e) mx = fmaxf(mx, bf2f((unsigned short)sv[e]));
        }
        #pragma unroll
        for (int off = 16; off; off >>= 1) mx = fmaxf(mx, __shfl_xor(mx, off, 32));
        float sum = 0.f;
        #pragma unroll
        for (int j = 0; j < 4; ++j) {
            shortx8 sv = *(const shortx8*)&Sraw[r][j * 256 + l * 8];
            shortx8 ev;
            #pragma unroll
            for (int e = 0; e < 8; ++e) {
                float x = __expf(bf2f((unsigned short)sv[e]) - mx);  // exp(-inf)=0
                sum += x;
                ev[e] = (short)f2bf(x);
            }
            *(shortx8*)&Sraw[r][j * 256 + l * 8] = ev;
        }
        #pragma unroll
        for (int off = 16; off; off >>= 1) sum += __shfl_xor(sum, off, 32);
        if (l == 0) invs[r] = 1.0f / sum;
    }
    __syncthreads();

    // ---- Pass 2b: write normalized p_attn (float2 per thread, coalesced) ----
    {
        float* prow = pout + ((size_t)((h * BATCH + b) * SEQ + n0)) * SEQ;
        #pragma unroll
        for (int i = 0; i < RB; ++i) {
            const float inv = invs[i];
            unsigned pk = *(const unsigned*)&Sraw[i][t * 2];
            float2 pv = { bf2f((unsigned short)(pk & 0xFFFFu)) * inv,
                          bf2f((unsigned short)(pk >> 16)) * inv };
            *(float2*)(prow + (size_t)i * SEQ + t * 2) = pv;
        }
    }

    // ---- Pass 3: O = (E V) * inv. m-range split across wave halves. ----
    const int hm = w >> 2;            // m-half 0/1
    const int c  = (w & 3) * 16;      // output col slice
    floatx4 acco = {0.f, 0.f, 0.f, 0.f};
    for (int mc = 0; mc < 8; ++mc) {
        #pragma unroll
        for (int s = 0; s < 2; ++s) {
            const int kb = hm * 512 + mc * 64 + s * 32 + qd * 8;
            float vv[8];                               // V col gather (L2)
            #pragma unroll
            for (int j = 0; j < 8; ++j)
                vv[j] = vbase[(size_t)(kb + j) * CH + c + ln];
            shortx8 af = *(const shortx8*)&Sraw[ln][kb];  // A[m=ln][k]
            shortx8 bfv;
            #pragma unroll
            for (int j = 0; j < 8; ++j) bfv[j] = (short)f2bf(vv[j]);
            acco = __builtin_amdgcn_mfma_f32_16x16x32_bf16(af, bfv, acco, 0, 0, 0);
        }
    }
    if (hm == 1) {
        #pragma unroll
        for (int r = 0; r < 4; ++r) Opart[qd * 4 + r][c + ln] = acco[r];
    }
    __syncthreads();
    if (hm == 0) {
        #pragma unroll
        for (int r = 0; r < 4; ++r) {
            int row = qd * 4 + r;
            out[((size_t)(b * SEQ + n0 + row)) * CH + h * DH + c + ln]
                = (acco[r] + Opart[row][c + ln]) * invs[row];
        }
    }
}

extern "C" void kernel_launch(void* const* d_in, const int* in_sizes, int n_in,
                              void* d_out, int out_size, void* d_ws, size_t ws_size,
                              hipStream_t stream) {
    const float* q    = (const float*)d_in[0];
    const float* k    = (const float*)d_in[1];
    const float* v    = (const float*)d_in[2];
    const void*  mask = d_in[3];
    const float* dis  = (const float*)d_in[4];
    float* out  = (float*)d_out;
    float* pout = out + (size_t)BATCH * SEQ * CH;   // p_attn after out
    (void)d_ws; (void)ws_size;

    attn_mfma<<<HEADS * BATCH * (SEQ / RB), NTHR, 0, stream>>>(
        q, k, v, mask, dis, out, pout);
}